// Round 1
// baseline (105.214 us; speedup 1.0000x reference)
//
#include <hip/hip_runtime.h>
#include <math.h>

// RegionLoss (YOLOv2) fused forward: scalar fp32 loss.
// Layout: output (NB, NA, 5+NC, NH, NW) fp32; target (NB, MAXB*5); anchors (10).

#define NCc 20
#define NAc 5
#define NBc 64
#define NHc 38
#define NWc 38
#define MAXBc 50
#define NHWc (NHc * NWc)          // 1444
#define CELLS_PER_B (NAc * NHWc)  // 7220
#define BPB 29                    // ceil(7220 / 256)
#define THRESHc 0.6f
#define OBJc 5.0f

__global__ void zero_out_kernel(float* out) { out[0] = 0.0f; }

__global__ __launch_bounds__(256) void region_loss_kernel(
    const float* __restrict__ outp, const float* __restrict__ target,
    const float* __restrict__ anchors, float* __restrict__ loss_out)
{
    __shared__ float s_gx[MAXBc], s_gy[MAXBc], s_gw[MAXBc], s_gh[MAXBc];
    __shared__ float s_tx[MAXBc], s_ty[MAXBc], s_tw[MAXBc], s_th[MAXBc];
    __shared__ int   s_meta[MAXBc];   // bn | gi<<3 | gj<<9 | cls<<15
    __shared__ int   s_nvalid;
    __shared__ float s_aw[NAc], s_ah[NAc];
    __shared__ float s_red[4];

    const int tid  = threadIdx.x;
    const int b    = blockIdx.x / BPB;
    const int cell = (blockIdx.x % BPB) * 256 + tid;

    if (tid < NAc) {
        s_aw[tid] = anchors[2 * tid];
        s_ah[tid] = anchors[2 * tid + 1];
    }

    // ---- wave 0: parse this batch's ground-truth boxes ----
    if (tid < 64) {
        const float* tb = target + (size_t)b * (MAXBc * 5);
        float gxn = (tid < MAXBc) ? tb[tid * 5 + 1] : 0.0f;
        unsigned long long m = __ballot(gxn != 0.0f);
        int nv = (int)__builtin_ctzll(~m);   // length of valid prefix (cumprod semantics)
        if (tid == 0) s_nvalid = nv;
        if (tid < nv) {
            float gx = gxn * (float)NWc;
            float gy = tb[tid * 5 + 2] * (float)NHc;
            float gw = tb[tid * 5 + 3] * (float)NWc;
            float gh = tb[tid * 5 + 4] * (float)NHc;
            int   cc = (int)tb[tid * 5 + 0];
            // best anchor: argmax of anchor-vs-gt IoU (co-centered); strict > keeps first max
            int bn = 0; float best = -1.0f;
            #pragma unroll
            for (int a = 0; a < NAc; ++a) {
                float aw = anchors[2 * a], ah = anchors[2 * a + 1];
                float inter = fminf(aw, gw) * fminf(ah, gh);
                float uni   = aw * ah + gw * gh - inter;
                float r = inter / uni;
                if (r > best) { best = r; bn = a; }
            }
            int gi = (int)gx; gi = min(max(gi, 0), NWc - 1);
            int gj = (int)gy; gj = min(max(gj, 0), NHc - 1);
            s_gx[tid] = gx; s_gy[tid] = gy; s_gw[tid] = gw; s_gh[tid] = gh;
            s_tx[tid] = gx - (float)gi;
            s_ty[tid] = gy - (float)gj;
            s_tw[tid] = __logf(gw / anchors[2 * bn]);
            s_th[tid] = __logf(gh / anchors[2 * bn + 1]);
            s_meta[tid] = bn | (gi << 3) | (gj << 9) | (cc << 15);
        }
    }
    __syncthreads();

    float lsum = 0.0f;
    if (cell < CELLS_PER_B) {
        const int a   = cell / NHWc;
        const int rem = cell - a * NHWc;
        const int j   = rem / NWc;
        const int i   = rem - j * NWc;

        const float* p = outp + ((size_t)(b * NAc + a) * (5 + NCc)) * NHWc + rem;
        float xr = p[0];
        float yr = p[NHWc];
        float wr = p[2 * NHWc];
        float hr = p[3 * NHWc];
        float cr = p[4 * NHWc];

        float x    = 1.0f / (1.0f + __expf(-xr));
        float y    = 1.0f / (1.0f + __expf(-yr));
        float conf = 1.0f / (1.0f + __expf(-cr));
        float pw = __expf(wr) * s_aw[a];
        float ph = __expf(hr) * s_ah[a];
        float px = x + (float)i;
        float py = y + (float)j;

        const int key = a | (i << 3) | (j << 9);
        float maxiou = 0.0f;
        float miou   = 0.0f;
        int   tmatch = -1;
        const int nv = s_nvalid;
        for (int t = 0; t < nv; ++t) {
            float gx = s_gx[t], gy = s_gy[t], gw = s_gw[t], gh = s_gh[t];
            float mx = fminf(px - pw * 0.5f, gx - gw * 0.5f);
            float Mx = fmaxf(px + pw * 0.5f, gx + gw * 0.5f);
            float my = fminf(py - ph * 0.5f, gy - gh * 0.5f);
            float My = fmaxf(py + ph * 0.5f, gy + gh * 0.5f);
            float cw = pw + gw - (Mx - mx);
            float chh = ph + gh - (My - my);
            float inter = (cw <= 0.0f || chh <= 0.0f) ? 0.0f : cw * chh;
            float uni = pw * ph + gw * gh - inter;
            float iou = inter / uni;
            maxiou = fmaxf(maxiou, iou);
            if ((s_meta[t] & 0x7FFF) == key) { tmatch = t; miou = iou; }
        }

        float tx, ty, tw, th, tc, cm;
        if (tmatch >= 0) {
            tx = s_tx[tmatch]; ty = s_ty[tmatch];
            tw = s_tw[tmatch]; th = s_th[tmatch];
            tc = miou; cm = OBJc;
        } else {
            tx = 0.5f; ty = 0.5f; tw = 0.0f; th = 0.0f; tc = 0.0f;
            cm = (maxiou > THRESHc) ? 0.0f : 1.0f;
        }
        float dx = x - tx, dy = y - ty, dw = wr - tw, dh = hr - th, dc = conf - tc;
        lsum = 0.5f * (dx * dx + dy * dy + dw * dw + dh * dh) + 0.5f * cm * dc * dc;

        // class NLL at target cells only (~9 per batch)
        if (tmatch >= 0) {
            int c = s_meta[tmatch] >> 15;
            const float* q = p + 5 * NHWc;
            float vals[NCc];
            float m = -1e30f, vc = 0.0f;
            #pragma unroll
            for (int k = 0; k < NCc; ++k) {
                vals[k] = q[k * NHWc];
                m = fmaxf(m, vals[k]);
                if (k == c) vc = vals[k];
            }
            float s = 0.0f;
            #pragma unroll
            for (int k = 0; k < NCc; ++k) s += __expf(vals[k] - m);
            lsum += (m + __logf(s)) - vc;
        }
    }

    // ---- reduce: wave shuffle -> LDS -> one atomic per block ----
    float w = lsum;
    #pragma unroll
    for (int off = 32; off > 0; off >>= 1) w += __shfl_down(w, off, 64);
    if ((tid & 63) == 0) s_red[tid >> 6] = w;
    __syncthreads();
    if (tid == 0) {
        float tot = s_red[0] + s_red[1] + s_red[2] + s_red[3];
        atomicAdd(loss_out, tot);
    }
}

extern "C" void kernel_launch(void* const* d_in, const int* in_sizes, int n_in,
                              void* d_out, int out_size, void* d_ws, size_t ws_size,
                              hipStream_t stream) {
    const float* outp    = (const float*)d_in[0];
    const float* target  = (const float*)d_in[1];
    const float* anchors = (const float*)d_in[2];
    float* loss = (float*)d_out;

    zero_out_kernel<<<1, 1, 0, stream>>>(loss);
    region_loss_kernel<<<NBc * BPB, 256, 0, stream>>>(outp, target, anchors, loss);
}

// Round 2
// 94.229 us; speedup vs baseline: 1.1166x; 1.1166x over previous
//
#include <hip/hip_runtime.h>
#include <math.h>

// RegionLoss (YOLOv2) fused forward: scalar fp32 loss.
// Layout: output (NB, NA, 5+NC, NH, NW) fp32; target (NB, MAXB*5); anchors (10).
// R2: float4 loads (4 cells/thread), 512 blocks, memset node instead of zero kernel.

#define NCc 20
#define NAc 5
#define NBc 64
#define NHc 38
#define NWc 38
#define MAXBc 50
#define NHWc (NHc * NWc)          // 1444 (divisible by 4)
#define CELLS_PER_B (NAc * NHWc)  // 7220 = 4 * 1805
#define BPB 8                     // 8 blocks/batch * 256 thr * 4 cells = 8192 >= 7220
#define THRESHc 0.6f
#define OBJc 5.0f

__global__ __launch_bounds__(256) void region_loss_kernel(
    const float* __restrict__ outp, const float* __restrict__ target,
    const float* __restrict__ anchors, float* __restrict__ loss_out)
{
    __shared__ float s_gx[MAXBc], s_gy[MAXBc], s_gw[MAXBc], s_gh[MAXBc];
    __shared__ float s_tx[MAXBc], s_ty[MAXBc], s_tw[MAXBc], s_th[MAXBc];
    __shared__ int   s_meta[MAXBc];   // bn | gi<<3 | gj<<9 | cls<<15
    __shared__ int   s_nvalid;
    __shared__ float s_aw[NAc], s_ah[NAc];
    __shared__ float s_red[4];

    const int tid = threadIdx.x;
    const int b   = blockIdx.x >> 3;          // blockIdx / BPB
    const int seg = blockIdx.x & 7;

    if (tid < NAc) {
        s_aw[tid] = anchors[2 * tid];
        s_ah[tid] = anchors[2 * tid + 1];
    }

    // ---- wave 0: parse this batch's ground-truth boxes ----
    if (tid < 64) {
        const float* tb = target + (size_t)b * (MAXBc * 5);
        float gxn = (tid < MAXBc) ? tb[tid * 5 + 1] : 0.0f;
        unsigned long long m = __ballot(gxn != 0.0f);
        int nv = (int)__builtin_ctzll(~m);   // valid-prefix length (cumprod semantics)
        if (tid == 0) s_nvalid = nv;
        if (tid < nv) {
            float gx = gxn * (float)NWc;
            float gy = tb[tid * 5 + 2] * (float)NHc;
            float gw = tb[tid * 5 + 3] * (float)NWc;
            float gh = tb[tid * 5 + 4] * (float)NHc;
            int   cc = (int)tb[tid * 5 + 0];
            int bn = 0; float best = -1.0f;
            #pragma unroll
            for (int a = 0; a < NAc; ++a) {
                float aw = anchors[2 * a], ah = anchors[2 * a + 1];
                float inter = fminf(aw, gw) * fminf(ah, gh);
                float uni   = aw * ah + gw * gh - inter;
                float r = inter / uni;
                if (r > best) { best = r; bn = a; }
            }
            int gi = (int)gx; gi = min(max(gi, 0), NWc - 1);
            int gj = (int)gy; gj = min(max(gj, 0), NHc - 1);
            s_gx[tid] = gx; s_gy[tid] = gy; s_gw[tid] = gw; s_gh[tid] = gh;
            s_tx[tid] = gx - (float)gi;
            s_ty[tid] = gy - (float)gj;
            s_tw[tid] = __logf(gw / anchors[2 * bn]);
            s_th[tid] = __logf(gh / anchors[2 * bn + 1]);
            s_meta[tid] = bn | (gi << 3) | (gj << 9) | (cc << 15);
        }
    }
    __syncthreads();

    float lsum = 0.0f;
    const int cell = seg * 1024 + tid * 4;    // 4 consecutive cells, same (a, channel row)
    if (cell < CELLS_PER_B) {
        const int a   = cell / NHWc;          // cells 4t..4t+3 share a (1444 % 4 == 0)
        const int rem = cell - a * NHWc;

        const float* p = outp + ((size_t)(b * NAc + a) * (5 + NCc)) * NHWc + rem;
        const float4 xr = *(const float4*)(p);
        const float4 yr = *(const float4*)(p + NHWc);
        const float4 wr = *(const float4*)(p + 2 * NHWc);
        const float4 hr = *(const float4*)(p + 3 * NHWc);
        const float4 cr = *(const float4*)(p + 4 * NHWc);
        const float xrv[4] = {xr.x, xr.y, xr.z, xr.w};
        const float yrv[4] = {yr.x, yr.y, yr.z, yr.w};
        const float wrv[4] = {wr.x, wr.y, wr.z, wr.w};
        const float hrv[4] = {hr.x, hr.y, hr.z, hr.w};
        const float crv[4] = {cr.x, cr.y, cr.z, cr.w};

        float x[4], y[4], conf[4], pw[4], ph[4], px[4], py[4];
        int key[4];
        #pragma unroll
        for (int k = 0; k < 4; ++k) {
            const int rk = rem + k;
            const int j  = rk / NWc;
            const int i  = rk - j * NWc;
            x[k]    = 1.0f / (1.0f + __expf(-xrv[k]));
            y[k]    = 1.0f / (1.0f + __expf(-yrv[k]));
            conf[k] = 1.0f / (1.0f + __expf(-crv[k]));
            pw[k] = __expf(wrv[k]) * s_aw[a];
            ph[k] = __expf(hrv[k]) * s_ah[a];
            px[k] = x[k] + (float)i;
            py[k] = y[k] + (float)j;
            key[k] = a | (i << 3) | (j << 9);
        }

        float maxiou[4] = {0.0f, 0.0f, 0.0f, 0.0f};
        float miou[4]   = {0.0f, 0.0f, 0.0f, 0.0f};
        int   tmatch[4] = {-1, -1, -1, -1};
        const int nv = s_nvalid;
        for (int t = 0; t < nv; ++t) {
            const float gx = s_gx[t], gy = s_gy[t], gw = s_gw[t], gh = s_gh[t];
            const int meta = s_meta[t] & 0x7FFF;
            #pragma unroll
            for (int k = 0; k < 4; ++k) {
                float mx = fminf(px[k] - pw[k] * 0.5f, gx - gw * 0.5f);
                float Mx = fmaxf(px[k] + pw[k] * 0.5f, gx + gw * 0.5f);
                float my = fminf(py[k] - ph[k] * 0.5f, gy - gh * 0.5f);
                float My = fmaxf(py[k] + ph[k] * 0.5f, gy + gh * 0.5f);
                float cw  = pw[k] + gw - (Mx - mx);
                float chh = ph[k] + gh - (My - my);
                float inter = (cw <= 0.0f || chh <= 0.0f) ? 0.0f : cw * chh;
                float uni = pw[k] * ph[k] + gw * gh - inter;
                float iou = inter / uni;
                maxiou[k] = fmaxf(maxiou[k], iou);
                if (meta == key[k]) { tmatch[k] = t; miou[k] = iou; }
            }
        }

        #pragma unroll
        for (int k = 0; k < 4; ++k) {
            float tx, ty, tw, th, tc, cm;
            if (tmatch[k] >= 0) {
                tx = s_tx[tmatch[k]]; ty = s_ty[tmatch[k]];
                tw = s_tw[tmatch[k]]; th = s_th[tmatch[k]];
                tc = miou[k]; cm = OBJc;
            } else {
                tx = 0.5f; ty = 0.5f; tw = 0.0f; th = 0.0f; tc = 0.0f;
                cm = (maxiou[k] > THRESHc) ? 0.0f : 1.0f;
            }
            float dx = x[k] - tx, dy = y[k] - ty;
            float dw = wrv[k] - tw, dh = hrv[k] - th, dc = conf[k] - tc;
            lsum += 0.5f * (dx * dx + dy * dy + dw * dw + dh * dh) + 0.5f * cm * dc * dc;

            if (tmatch[k] >= 0) {   // class NLL at target cells only (~9/batch)
                int c = s_meta[tmatch[k]] >> 15;
                const float* q = p + k + 5 * NHWc;
                float vals[NCc];
                float mm = -1e30f, vc = 0.0f;
                #pragma unroll
                for (int kk = 0; kk < NCc; ++kk) {
                    vals[kk] = q[kk * NHWc];
                    mm = fmaxf(mm, vals[kk]);
                    if (kk == c) vc = vals[kk];
                }
                float s = 0.0f;
                #pragma unroll
                for (int kk = 0; kk < NCc; ++kk) s += __expf(vals[kk] - mm);
                lsum += (mm + __logf(s)) - vc;
            }
        }
    }

    // ---- reduce: wave shuffle -> LDS -> one atomic per block ----
    float w = lsum;
    #pragma unroll
    for (int off = 32; off > 0; off >>= 1) w += __shfl_down(w, off, 64);
    if ((tid & 63) == 0) s_red[tid >> 6] = w;
    __syncthreads();
    if (tid == 0) {
        float tot = s_red[0] + s_red[1] + s_red[2] + s_red[3];
        atomicAdd(loss_out, tot);
    }
}

extern "C" void kernel_launch(void* const* d_in, const int* in_sizes, int n_in,
                              void* d_out, int out_size, void* d_ws, size_t ws_size,
                              hipStream_t stream) {
    const float* outp    = (const float*)d_in[0];
    const float* target  = (const float*)d_in[1];
    const float* anchors = (const float*)d_in[2];
    float* loss = (float*)d_out;

    hipMemsetAsync(loss, 0, sizeof(float), stream);   // graph-capturable memset node
    region_loss_kernel<<<NBc * BPB, 256, 0, stream>>>(outp, target, anchors, loss);
}